// Round 5
// baseline (138.343 us; speedup 1.0000x reference)
//
#include <hip/hip_runtime.h>
#include <hip/hip_bf16.h>

// LSTM_71382356459716 R13: waveLSTM + explicit wave-local LDS fences.
// R12 post-mortem: FAILED absmax 3.03e-2 (4x threshold, not 100x). Layout
// chain re-verified by hand (pi/h-store/FC/W_hh consistent; frag maps
// identical to passing R8-R11) -> small error = stale-by-one-step h/x reads.
// R12's only novelty was relying on IMPLICIT same-wave LDS ordering across
// type-punned accesses with zero fences; every passing kernel had
// __syncthreads (= compiler fence + lgkmcnt drain) there.
// R13: same structure, but explicit `s_waitcnt lgkmcnt(0)` + sched_barrier(0)
// (rule #18) at: LDS-init->bias, staging->loop, loop top (h/x writes of step
// t-1 -> B-frag reads of step t), loop->epilogue. No vmcnt drain -> x
// prefetch stays in flight; no cross-wave coupling (1 wave/block).
// Kept from R12: 1024 one-wave blocks (1 wave/SIMD, 4/CU exact fit), 16
// M-tiles x 3 kchunks stationary A (192 VGPR, unified VGPR/AGPR file), 16
// independent unit chains/lane, pi(c)=4*(c&15)+(c>>4) -> 2 ds_write_b128
// h-store, exp2-folded weights, rcp-paired activations, zero s_barrier.
// Prediction: passes ~2e-3; 20-30us; VALUBusy 70-90%; Occupancy ~10% (by
// design). If still 3e-2 -> layout bug after all -> bisect pi next.

namespace {
constexpr int B_TOT   = 16384;
constexpr int T_STEPS = 28;
constexpr int IN_DIM  = 28;
constexpr int HID     = 64;
constexpr int OUT_DIM = 10;
constexpr int ROWS    = 16;    // batch rows per wave -> 1024 waves, 1/SIMD
constexpr int THREADS = 64;    // 1 wave per block
constexpr int KP      = 104;   // row stride in shorts (208 B = 13*16B)
constexpr int XROW    = T_STEPS * IN_DIM;  // 784 floats per batch row
constexpr int NFRAG   = 16 * 3;            // 16 Mtiles * 3 kchunks
constexpr int WS_ELEMS = NFRAG * 64 * 8;   // 24576 bf16 = 48 KB
}

typedef __attribute__((ext_vector_type(8))) short short8v;   // 8 bf16
typedef __attribute__((ext_vector_type(4))) short short4v;
typedef __attribute__((ext_vector_type(4))) float float4v;

__device__ __forceinline__ void lds_fence() {
  // Order all prior LDS ops before any later ones; no vmcnt drain.
  asm volatile("s_waitcnt lgkmcnt(0)" ::: "memory");
  __builtin_amdgcn_sched_barrier(0);   // rule #18: block reordering past it
}

__device__ __forceinline__ short f2bf_cold(float f) {
  union { float f; unsigned u; } v; v.f = f;
  unsigned r = v.u + 0x7FFFu + ((v.u >> 16) & 1u);
  return (short)(r >> 16);
}
__device__ __forceinline__ float bf2f(short s) {
  union { unsigned u; float f; } v; v.u = ((unsigned)(unsigned short)s) << 16;
  return v.f;
}
__device__ __forceinline__ unsigned pk2(float a, float b) {  // 2xf32->bf16x2
  __hip_bfloat162 h = __float22bfloat162_rn(float2{a, b});
  union { __hip_bfloat162 h; unsigned u; } cv; cv.h = h; return cv.u;
}

// ---- setup: permute weights+bias into MFMA A-frag order (runs every call) --
// ws layout: frag f = mt*3 + kc, lane l, elem j:
//   ws[(f*64 + l)*8 + j] = bf16 of A[m=16*mt+(l&15)][k=kc*32+(l>>4)*8+j]
// gate row g = (m&3)*64 + (m>>2); k<28 -> W_ih, k==28 -> b_ih+b_hh,
// 29..31 -> 0, k>=32 -> W_hh[:, u(k-32)] where stored h col c holds unit
// u(c) = 4*(c&15) + (c>>4)   [pi: lane (q,l15) writes units 4mt+q at
// col 16q+mt, contiguous per lane].
// All values pre-scaled by -log2(e) (gates i,f,o) / -2*log2(e) (gate g) so
// the main kernel uses bare exp2.
__global__ void lstm_prep(const float* __restrict__ W_ih,
                          const float* __restrict__ W_hh,
                          const float* __restrict__ b_ih,
                          const float* __restrict__ b_hh,
                          unsigned short* __restrict__ ws) {
  int idx = blockIdx.x * blockDim.x + threadIdx.x;
  if (idx >= WS_ELEMS) return;
  int j  = idx & 7;
  int l  = (idx >> 3) & 63;
  int fk = idx >> 9;            // mt*3 + kc
  int kc = fk % 3;
  int mt = fk / 3;
  int m  = 16 * mt + (l & 15);
  int unit = m >> 2, type = m & 3;
  int g  = type * 64 + unit;
  int k  = kc * 32 + (l >> 4) * 8 + j;
  float v = 0.0f;
  if (k < IN_DIM)        v = W_ih[g * IN_DIM + k];
  else if (k == IN_DIM)  v = b_ih[g] + b_hh[g];
  else if (k >= 32) {
    int c = k - 32;
    int u = 4 * (c & 15) + (c >> 4);   // pi
    v = W_hh[g * HID + u];
  }
  // fold exp argument scaling into the weights (type 2 == gate g -> tanh)
  v *= (type == 2) ? -2.8853900817779268f : -1.4426950408889634f;
  ws[idx] = (unsigned short)f2bf_cold(v);
}

__global__ __attribute__((amdgpu_flat_work_group_size(THREADS, THREADS),
                          amdgpu_waves_per_eu(1, 1)))
void lstm_wave(const float* __restrict__ x,
               const unsigned short* __restrict__ wfrag,
               const float* __restrict__ W_fc,
               const float* __restrict__ b_fc, float* __restrict__ out) {
  // wave-private: [buf][row][k]: 0..27 x, 28 = 1.0 (bias), 32..95 h (pi-perm)
  __shared__ __align__(16) short hs[2][ROWS][KP];

  const int lane = threadIdx.x & 63;
  const int l15  = lane & 15;
  const int q    = lane >> 4;     // 0..3
  const int b0   = blockIdx.x * ROWS;

  // ---- stationary A: all 16 M-tiles, 48 coalesced 16B loads per lane ------
  // (192 regs; gfx950 unified VGPR/AGPR file, MFMA reads A from either)
  short8v a[16][3];
#pragma unroll
  for (int mt = 0; mt < 16; ++mt)
#pragma unroll
    for (int kc = 0; kc < 3; ++kc)
      a[mt][kc] = *(const short8v*)&wfrag[(((mt * 3) + kc) * 64 + lane) * 8];

  // zero both buffers (13 x short4 per lane), then the constant bias column
  {
    short4v z4 = {0, 0, 0, 0};
#pragma unroll
    for (int k2 = 0; k2 < 13; ++k2)
      ((short4v*)&hs[0][0][0])[lane + 64 * k2] = z4;
  }
  lds_fence();   // zero-stores (cross-lane WAW on col 28) before bias write
  if (lane < 2 * ROWS)   // buf = lane>>4, row = lane&15
    hs[lane >> 4][lane & 15][IN_DIM] = (short)0x3F80;  // bf16 1.0

  // ---- x staging: 112 float4-slots per wave; lane covers {lane, lane+64} --
  const int  s0  = lane;            // always < 112
  const int  s1  = lane + 64;
  const bool st1 = (s1 < 112);      // lanes 0..47
  const int  sr0 = s0 / 7, sc0 = s0 - 7 * sr0;
  const int  sr1 = st1 ? (s1 / 7) : 0, sc1 = st1 ? (s1 - 7 * (s1 / 7)) : 0;
  const float* xp0 = x + (size_t)(b0 + sr0) * XROW + sc0 * 4;
  const float* xp1 = x + (size_t)(b0 + sr1) * XROW + sc1 * 4;

  // stage x_0 directly; preload x_1 into in-flight registers
  float4 fly0, fly1 = {0.f, 0.f, 0.f, 0.f};
  {
    float4 x0 = *(const float4*)xp0;
    short4v sv;
    unsigned plo = pk2(x0.x, x0.y), phi = pk2(x0.z, x0.w);
    sv[0] = (short)(plo & 0xFFFF); sv[1] = (short)(plo >> 16);
    sv[2] = (short)(phi & 0xFFFF); sv[3] = (short)(phi >> 16);
    *(short4v*)&hs[0][sr0][sc0 * 4] = sv;
    if (st1) {
      float4 x1 = *(const float4*)xp1;
      unsigned qlo = pk2(x1.x, x1.y), qhi = pk2(x1.z, x1.w);
      sv[0] = (short)(qlo & 0xFFFF); sv[1] = (short)(qlo >> 16);
      sv[2] = (short)(qhi & 0xFFFF); sv[3] = (short)(qhi >> 16);
      *(short4v*)&hs[0][sr1][sc1 * 4] = sv;
    }
    fly0 = *(const float4*)(xp0 + 1 * IN_DIM);
    if (st1) fly1 = *(const float4*)(xp1 + 1 * IN_DIM);
  }

  float c_state[16];
#pragma unroll
  for (int mt = 0; mt < 16; ++mt) c_state[mt] = 0.f;

  for (int t = 0; t < T_STEPS; ++t) {
    const int cur = t & 1, nxt = cur ^ 1;

    // order prior-step h/x writes (and init staging at t=0) before reads
    lds_fence();

    // B-frags: lane holds B[k = kc*32 + q*8 + j][n = l15]
    short8v bf0 = *(const short8v*)&hs[cur][l15][q * 8];
    short8v bf1 = *(const short8v*)&hs[cur][l15][32 + q * 8];
    short8v bf2 = *(const short8v*)&hs[cur][l15][64 + q * 8];

    // store x_{t+1} (loaded a step ago), issue load of x_{t+2}
    if (t + 1 < T_STEPS) {
      short4v sv;
      unsigned plo = pk2(fly0.x, fly0.y), phi = pk2(fly0.z, fly0.w);
      sv[0] = (short)(plo & 0xFFFF); sv[1] = (short)(plo >> 16);
      sv[2] = (short)(phi & 0xFFFF); sv[3] = (short)(phi >> 16);
      *(short4v*)&hs[nxt][sr0][sc0 * 4] = sv;
      if (st1) {
        unsigned qlo = pk2(fly1.x, fly1.y), qhi = pk2(fly1.z, fly1.w);
        sv[0] = (short)(qlo & 0xFFFF); sv[1] = (short)(qlo >> 16);
        sv[2] = (short)(qhi & 0xFFFF); sv[3] = (short)(qhi >> 16);
        *(short4v*)&hs[nxt][sr1][sc1 * 4] = sv;
      }
      if (t + 2 < T_STEPS) {
        fly0 = *(const float4*)(xp0 + (t + 2) * IN_DIM);
        if (st1) fly1 = *(const float4*)(xp1 + (t + 2) * IN_DIM);
      }
    }

    // 16 M-tiles x 3 k-chunks; 16 independent 3-deep MFMA chains
    const float4v zero4 = {0.f, 0.f, 0.f, 0.f};
    float4v acc[16];
#pragma unroll
    for (int mt = 0; mt < 16; ++mt)
      acc[mt] = __builtin_amdgcn_mfma_f32_16x16x32_bf16(a[mt][0], bf0, zero4, 0, 0, 0);
#pragma unroll
    for (int mt = 0; mt < 16; ++mt)
      acc[mt] = __builtin_amdgcn_mfma_f32_16x16x32_bf16(a[mt][1], bf1, acc[mt], 0, 0, 0);
#pragma unroll
    for (int mt = 0; mt < 16; ++mt)
      acc[mt] = __builtin_amdgcn_mfma_f32_16x16x32_bf16(a[mt][2], bf2, acc[mt], 0, 0, 0);

    // activations: lane (q,l15) owns unit 4mt+q, row l15; regs j = i,f,g,o.
    // exp scales pre-folded -> bare exp2. 16 independent chains.
    float hv[16];
#pragma unroll
    for (int mt = 0; mt < 16; ++mt) {
      float4v g4 = acc[mt];
      float Ei = __builtin_amdgcn_exp2f(g4[0]);
      float Ef = __builtin_amdgcn_exp2f(g4[1]);
      float Eg = __builtin_amdgcn_exp2f(g4[2]);
      float Eo = __builtin_amdgcn_exp2f(g4[3]);
      float di = 1.0f + Ei, df = 1.0f + Ef;
      float r1 = __builtin_amdgcn_rcpf(di * df);
      float iv = r1 * df;
      float fv = r1 * di;
      float gv = fmaf(2.0f, __builtin_amdgcn_rcpf(1.0f + Eg), -1.0f);
      float cn = fmaf(fv, c_state[mt], iv * gv);
      c_state[mt] = cn;
      float ct = fminf(fmaxf(cn, -15.0f), 15.0f);   // tanh saturated beyond
      float Ec = __builtin_amdgcn_exp2f(-2.8853900817779268f * ct);
      float dn = 1.0f + Eo, dc = 1.0f + Ec;
      float r2 = __builtin_amdgcn_rcpf(dn * dc);
      float ov = r2 * dc;
      float tc = fmaf(2.0f * r2, dn, -1.0f);
      hv[mt] = ov * tc;
    }

    // pack 16 bf16 (units 4mt+q at cols 16q+mt, mt ascending) -> 2x b128
    union { unsigned u[4]; short8v s; } uh0, uh1;
#pragma unroll
    for (int p = 0; p < 4; ++p) uh0.u[p] = pk2(hv[2 * p], hv[2 * p + 1]);
#pragma unroll
    for (int p = 0; p < 4; ++p) uh1.u[p] = pk2(hv[8 + 2 * p], hv[9 + 2 * p]);
    *(short8v*)&hs[nxt][l15][32 + 16 * q]     = uh0.s;
    *(short8v*)&hs[nxt][l15][32 + 16 * q + 8] = uh1.s;
  }

  lds_fence();   // final h-writes before cross-lane epilogue reads

  // ---- FC epilogue: final h in hs[0]; stored col c holds unit u(c) --------
  // lane covers row er = lane>>2, outputs {eo, eo+4, eo+8(if<10)}
  {
    const int er = lane >> 2;      // 0..15
    const int eo = lane & 3;       // 0..3
    float s0a = b_fc[eo];
    float s1a = b_fc[eo + 4];
    float s2a = (eo < 2) ? b_fc[eo + 8] : 0.f;
#pragma unroll
    for (int c = 0; c < HID; ++c) {
      float hb = bf2f(hs[0][er][32 + c]);
      int u = 4 * (c & 15) + (c >> 4);
      s0a = fmaf(hb, W_fc[eo * HID + u], s0a);
      s1a = fmaf(hb, W_fc[(eo + 4) * HID + u], s1a);
      if (eo < 2) s2a = fmaf(hb, W_fc[(eo + 8) * HID + u], s2a);
    }
    float* orow = out + (size_t)(b0 + er) * OUT_DIM;
    orow[eo]     = s0a;
    orow[eo + 4] = s1a;
    if (eo < 2) orow[eo + 8] = s2a;
  }
}

extern "C" void kernel_launch(void* const* d_in, const int* in_sizes, int n_in,
                              void* d_out, int out_size, void* d_ws, size_t ws_size,
                              hipStream_t stream) {
  const float* x    = (const float*)d_in[0];
  const float* W_ih = (const float*)d_in[1];
  const float* W_hh = (const float*)d_in[2];
  const float* b_ih = (const float*)d_in[3];
  const float* b_hh = (const float*)d_in[4];
  const float* W_fc = (const float*)d_in[5];
  const float* b_fc = (const float*)d_in[6];
  float* out = (float*)d_out;
  unsigned short* ws = (unsigned short*)d_ws;   // 48 KB frag-ordered weights

  lstm_prep<<<(WS_ELEMS + 255) / 256, 256, 0, stream>>>(W_ih, W_hh, b_ih, b_hh, ws);

  dim3 grid(B_TOT / ROWS);   // 1024 one-wave blocks -> 1 wave/SIMD chip-wide
  dim3 block(THREADS);
  lstm_wave<<<grid, block, 0, stream>>>(x, ws, W_fc, b_fc, out);
}

// Round 6
// 138.276 us; speedup vs baseline: 1.0005x; 1.0005x over previous
//
#include <hip/hip_runtime.h>
#include <hip/hip_bf16.h>

// LSTM_71382356459716 R14: let the weights actually stay in registers.
// R13 post-mortem: passed, flat 59.7us. Decisive counter: VGPR_Count=160 but
// a[16][3] alone needs 192 VGPR -> compiler REMATERIALIZES the 48 A-frag
// loads from L2 EVERY TIMESTEP (48 global_load_dwordx4 + ~200cy latency x28).
// Root cause: loop-top fence asm had a "memory" clobber (R8-R11: __syncthreads
// same effect) -> weight values legally invalidated each iteration. This
// reload is the structure-invariant ~2000cy/step that made R9-R13 all flat;
// invisible in FETCH_SIZE because ws is L2-resident.
// R14 changes (surgical, nothing else):
//  (1) loop fence = s_waitcnt lgkmcnt(0) WITHOUT memory clobber +
//      sched_barrier(0): HW/sched ordering kept, register values not
//      clobbered -> A-frags can live across steps.
//  (2) t-loop unrolled x2 with compile-time cur/nxt: h-write -> h-read
//      ordering enforced by real same-array dependences.
//  (3) full-clobber fences only at prologue/epilogue (one-time).
// Kept from R13 (passed): 1024 one-wave blocks, 16 M-tiles stationary, pi
// permutation, exp2-folded weights, rcp-paired activations, zero s_barrier.
// Prediction: VGPR >=300, main 38-48us, VALUBusy 60-75%, absmax 0.00195.
// Failure tells: VGPR ~160 flat -> AGPR-pin next; VGPR up flat -> trans floor.

namespace {
constexpr int B_TOT   = 16384;
constexpr int T_STEPS = 28;
constexpr int IN_DIM  = 28;
constexpr int HID     = 64;
constexpr int OUT_DIM = 10;
constexpr int ROWS    = 16;    // batch rows per wave -> 1024 waves, 1/SIMD
constexpr int THREADS = 64;    // 1 wave per block
constexpr int KP      = 104;   // row stride in shorts (208 B = 13*16B)
constexpr int XROW    = T_STEPS * IN_DIM;  // 784 floats per batch row
constexpr int NFRAG   = 16 * 3;            // 16 Mtiles * 3 kchunks
constexpr int WS_ELEMS = NFRAG * 64 * 8;   // 24576 bf16 = 48 KB
}

typedef __attribute__((ext_vector_type(8))) short short8v;   // 8 bf16
typedef __attribute__((ext_vector_type(4))) short short4v;
typedef __attribute__((ext_vector_type(4))) float float4v;

// Full fence: one-time use (prologue/epilogue). Clobbers memory.
__device__ __forceinline__ void lds_fence_full() {
  asm volatile("s_waitcnt lgkmcnt(0)" ::: "memory");
  __builtin_amdgcn_sched_barrier(0);
}
// Surgical loop fence: HW drain + scheduler pin, NO value clobber.
__device__ __forceinline__ void lds_order() {
  asm volatile("s_waitcnt lgkmcnt(0)");
  __builtin_amdgcn_sched_barrier(0);
}

__device__ __forceinline__ short f2bf_cold(float f) {
  union { float f; unsigned u; } v; v.f = f;
  unsigned r = v.u + 0x7FFFu + ((v.u >> 16) & 1u);
  return (short)(r >> 16);
}
__device__ __forceinline__ float bf2f(short s) {
  union { unsigned u; float f; } v; v.u = ((unsigned)(unsigned short)s) << 16;
  return v.f;
}
__device__ __forceinline__ unsigned pk2(float a, float b) {  // 2xf32->bf16x2
  __hip_bfloat162 h = __float22bfloat162_rn(float2{a, b});
  union { __hip_bfloat162 h; unsigned u; } cv; cv.h = h; return cv.u;
}

// ---- setup: permute weights+bias into MFMA A-frag order (runs every call) --
// ws layout: frag f = mt*3 + kc, lane l, elem j:
//   ws[(f*64 + l)*8 + j] = bf16 of A[m=16*mt+(l&15)][k=kc*32+(l>>4)*8+j]
// gate row g = (m&3)*64 + (m>>2); k<28 -> W_ih, k==28 -> b_ih+b_hh,
// 29..31 -> 0, k>=32 -> W_hh[:, u(k-32)] where stored h col c holds unit
// u(c) = 4*(c&15) + (c>>4)   [pi: lane (q,l15) writes units 4mt+q at
// col 16q+mt, contiguous per lane].
// All values pre-scaled by -log2(e) (gates i,f,o) / -2*log2(e) (gate g).
__global__ void lstm_prep(const float* __restrict__ W_ih,
                          const float* __restrict__ W_hh,
                          const float* __restrict__ b_ih,
                          const float* __restrict__ b_hh,
                          unsigned short* __restrict__ ws) {
  int idx = blockIdx.x * blockDim.x + threadIdx.x;
  if (idx >= WS_ELEMS) return;
  int j  = idx & 7;
  int l  = (idx >> 3) & 63;
  int fk = idx >> 9;            // mt*3 + kc
  int kc = fk % 3;
  int mt = fk / 3;
  int m  = 16 * mt + (l & 15);
  int unit = m >> 2, type = m & 3;
  int g  = type * 64 + unit;
  int k  = kc * 32 + (l >> 4) * 8 + j;
  float v = 0.0f;
  if (k < IN_DIM)        v = W_ih[g * IN_DIM + k];
  else if (k == IN_DIM)  v = b_ih[g] + b_hh[g];
  else if (k >= 32) {
    int c = k - 32;
    int u = 4 * (c & 15) + (c >> 4);   // pi
    v = W_hh[g * HID + u];
  }
  v *= (type == 2) ? -2.8853900817779268f : -1.4426950408889634f;
  ws[idx] = (unsigned short)f2bf_cold(v);
}

__global__ __attribute__((amdgpu_flat_work_group_size(THREADS, THREADS),
                          amdgpu_waves_per_eu(1, 1)))
void lstm_wave(const float* __restrict__ x,
               const unsigned short* __restrict__ wfrag,
               const float* __restrict__ W_fc,
               const float* __restrict__ b_fc, float* __restrict__ out) {
  // wave-private: [buf][row][k]: 0..27 x, 28 = 1.0 (bias), 32..95 h (pi-perm)
  __shared__ __align__(16) short hs[2][ROWS][KP];

  const int lane = threadIdx.x & 63;
  const int l15  = lane & 15;
  const int q    = lane >> 4;     // 0..3
  const int b0   = blockIdx.x * ROWS;

  // ---- stationary A: all 16 M-tiles, 48 coalesced 16B loads per lane ------
  short8v a[16][3];
#pragma unroll
  for (int mt = 0; mt < 16; ++mt)
#pragma unroll
    for (int kc = 0; kc < 3; ++kc)
      a[mt][kc] = *(const short8v*)&wfrag[(((mt * 3) + kc) * 64 + lane) * 8];

  // zero both buffers (13 x short4 per lane), then the constant bias column
  {
    short4v z4 = {0, 0, 0, 0};
#pragma unroll
    for (int k2 = 0; k2 < 13; ++k2)
      ((short4v*)&hs[0][0][0])[lane + 64 * k2] = z4;
  }
  lds_fence_full();   // one-time: zero-stores before bias write
  if (lane < 2 * ROWS)   // buf = lane>>4, row = lane&15
    hs[lane >> 4][lane & 15][IN_DIM] = (short)0x3F80;  // bf16 1.0

  // ---- x staging: 112 float4-slots per wave; lane covers {lane, lane+64} --
  const int  s0  = lane;            // always < 112
  const int  s1  = lane + 64;
  const bool st1 = (s1 < 112);      // lanes 0..47
  const int  sr0 = s0 / 7, sc0 = s0 - 7 * sr0;
  const int  sr1 = st1 ? (s1 / 7) : 0, sc1 = st1 ? (s1 - 7 * (s1 / 7)) : 0;
  const float* xp0 = x + (size_t)(b0 + sr0) * XROW + sc0 * 4;
  const float* xp1 = x + (size_t)(b0 + sr1) * XROW + sc1 * 4;

  // stage x_0 directly; preload x_1 into in-flight registers
  float4 fly0, fly1 = {0.f, 0.f, 0.f, 0.f};
  {
    float4 x0 = *(const float4*)xp0;
    short4v sv;
    unsigned plo = pk2(x0.x, x0.y), phi = pk2(x0.z, x0.w);
    sv[0] = (short)(plo & 0xFFFF); sv[1] = (short)(plo >> 16);
    sv[2] = (short)(phi & 0xFFFF); sv[3] = (short)(phi >> 16);
    *(short4v*)&hs[0][sr0][sc0 * 4] = sv;
    if (st1) {
      float4 x1 = *(const float4*)xp1;
      unsigned qlo = pk2(x1.x, x1.y), qhi = pk2(x1.z, x1.w);
      sv[0] = (short)(qlo & 0xFFFF); sv[1] = (short)(qlo >> 16);
      sv[2] = (short)(qhi & 0xFFFF); sv[3] = (short)(qhi >> 16);
      *(short4v*)&hs[0][sr1][sc1 * 4] = sv;
    }
    fly0 = *(const float4*)(xp0 + 1 * IN_DIM);
    if (st1) fly1 = *(const float4*)(xp1 + 1 * IN_DIM);
  }
  lds_fence_full();   // one-time: staging visible before step 0 reads

  float c_state[16];
#pragma unroll
  for (int mt = 0; mt < 16; ++mt) c_state[mt] = 0.f;

  // ---- one timestep, compile-time buffer indices ---------------------------
  auto step = [&](int t, int cur, int nxt) __attribute__((always_inline)) {
    // order prior-step h/x writes before this step's reads (no value clobber)
    lds_order();

    // B-frags: lane holds B[k = kc*32 + q*8 + j][n = l15]
    short8v bf0 = *(const short8v*)&hs[cur][l15][q * 8];
    short8v bf1 = *(const short8v*)&hs[cur][l15][32 + q * 8];
    short8v bf2 = *(const short8v*)&hs[cur][l15][64 + q * 8];

    // store x_{t+1} (loaded a step ago), issue load of x_{t+2}
    if (t + 1 < T_STEPS) {
      short4v sv;
      unsigned plo = pk2(fly0.x, fly0.y), phi = pk2(fly0.z, fly0.w);
      sv[0] = (short)(plo & 0xFFFF); sv[1] = (short)(plo >> 16);
      sv[2] = (short)(phi & 0xFFFF); sv[3] = (short)(phi >> 16);
      *(short4v*)&hs[nxt][sr0][sc0 * 4] = sv;
      if (st1) {
        unsigned qlo = pk2(fly1.x, fly1.y), qhi = pk2(fly1.z, fly1.w);
        sv[0] = (short)(qlo & 0xFFFF); sv[1] = (short)(qlo >> 16);
        sv[2] = (short)(qhi & 0xFFFF); sv[3] = (short)(qhi >> 16);
        *(short4v*)&hs[nxt][sr1][sc1 * 4] = sv;
      }
      if (t + 2 < T_STEPS) {
        fly0 = *(const float4*)(xp0 + (t + 2) * IN_DIM);
        if (st1) fly1 = *(const float4*)(xp1 + (t + 2) * IN_DIM);
      }
    }

    // 16 M-tiles x 3 k-chunks; 16 independent 3-deep MFMA chains
    const float4v zero4 = {0.f, 0.f, 0.f, 0.f};
    float4v acc[16];
#pragma unroll
    for (int mt = 0; mt < 16; ++mt)
      acc[mt] = __builtin_amdgcn_mfma_f32_16x16x32_bf16(a[mt][0], bf0, zero4, 0, 0, 0);
#pragma unroll
    for (int mt = 0; mt < 16; ++mt)
      acc[mt] = __builtin_amdgcn_mfma_f32_16x16x32_bf16(a[mt][1], bf1, acc[mt], 0, 0, 0);
#pragma unroll
    for (int mt = 0; mt < 16; ++mt)
      acc[mt] = __builtin_amdgcn_mfma_f32_16x16x32_bf16(a[mt][2], bf2, acc[mt], 0, 0, 0);

    // activations: lane (q,l15) owns unit 4mt+q, row l15; regs j = i,f,g,o.
    float hv[16];
#pragma unroll
    for (int mt = 0; mt < 16; ++mt) {
      float4v g4 = acc[mt];
      float Ei = __builtin_amdgcn_exp2f(g4[0]);
      float Ef = __builtin_amdgcn_exp2f(g4[1]);
      float Eg = __builtin_amdgcn_exp2f(g4[2]);
      float Eo = __builtin_amdgcn_exp2f(g4[3]);
      float di = 1.0f + Ei, df = 1.0f + Ef;
      float r1 = __builtin_amdgcn_rcpf(di * df);
      float iv = r1 * df;
      float fv = r1 * di;
      float gv = fmaf(2.0f, __builtin_amdgcn_rcpf(1.0f + Eg), -1.0f);
      float cn = fmaf(fv, c_state[mt], iv * gv);
      c_state[mt] = cn;
      float ct = fminf(fmaxf(cn, -15.0f), 15.0f);   // tanh saturated beyond
      float Ec = __builtin_amdgcn_exp2f(-2.8853900817779268f * ct);
      float dn = 1.0f + Eo, dc = 1.0f + Ec;
      float r2 = __builtin_amdgcn_rcpf(dn * dc);
      float ov = r2 * dc;
      float tc = fmaf(2.0f * r2, dn, -1.0f);
      hv[mt] = ov * tc;
    }

    // pack 16 bf16 (units 4mt+q at cols 16q+mt, mt ascending) -> 2x b128
    union { unsigned u[4]; short8v s; } uh0, uh1;
#pragma unroll
    for (int p = 0; p < 4; ++p) uh0.u[p] = pk2(hv[2 * p], hv[2 * p + 1]);
#pragma unroll
    for (int p = 0; p < 4; ++p) uh1.u[p] = pk2(hv[8 + 2 * p], hv[9 + 2 * p]);
    *(short8v*)&hs[nxt][l15][32 + 16 * q]     = uh0.s;
    *(short8v*)&hs[nxt][l15][32 + 16 * q + 8] = uh1.s;
  };

  // unrolled x2: compile-time cur/nxt -> static aliasing enforces ordering
  for (int tt = 0; tt < T_STEPS / 2; ++tt) {
    step(2 * tt,     0, 1);
    step(2 * tt + 1, 1, 0);
  }

  lds_fence_full();   // one-time: final h-writes before cross-lane epilogue

  // ---- FC epilogue: final h in hs[0]; stored col c holds unit u(c) --------
  {
    const int er = lane >> 2;      // 0..15
    const int eo = lane & 3;       // 0..3
    float s0a = b_fc[eo];
    float s1a = b_fc[eo + 4];
    float s2a = (eo < 2) ? b_fc[eo + 8] : 0.f;
#pragma unroll
    for (int c = 0; c < HID; ++c) {
      float hb = bf2f(hs[0][er][32 + c]);
      int u = 4 * (c & 15) + (c >> 4);
      s0a = fmaf(hb, W_fc[eo * HID + u], s0a);
      s1a = fmaf(hb, W_fc[(eo + 4) * HID + u], s1a);
      if (eo < 2) s2a = fmaf(hb, W_fc[(eo + 8) * HID + u], s2a);
    }
    float* orow = out + (size_t)(b0 + er) * OUT_DIM;
    orow[eo]     = s0a;
    orow[eo + 4] = s1a;
    if (eo < 2) orow[eo + 8] = s2a;
  }
}

extern "C" void kernel_launch(void* const* d_in, const int* in_sizes, int n_in,
                              void* d_out, int out_size, void* d_ws, size_t ws_size,
                              hipStream_t stream) {
  const float* x    = (const float*)d_in[0];
  const float* W_ih = (const float*)d_in[1];
  const float* W_hh = (const float*)d_in[2];
  const float* b_ih = (const float*)d_in[3];
  const float* b_hh = (const float*)d_in[4];
  const float* W_fc = (const float*)d_in[5];
  const float* b_fc = (const float*)d_in[6];
  float* out = (float*)d_out;
  unsigned short* ws = (unsigned short*)d_ws;   // 48 KB frag-ordered weights

  lstm_prep<<<(WS_ELEMS + 255) / 256, 256, 0, stream>>>(W_ih, W_hh, b_ih, b_hh, ws);

  dim3 grid(B_TOT / ROWS);   // 1024 one-wave blocks -> 1 wave/SIMD chip-wide
  dim3 block(THREADS);
  lstm_wave<<<grid, block, 0, stream>>>(x, ws, W_fc, b_fc, out);
}

// Round 7
// 137.582 us; speedup vs baseline: 1.0055x; 1.0050x over previous
//
#include <hip/hip_runtime.h>
#include <hip/hip_bf16.h>

// LSTM_71382356459716 R15: pin weight fragments in AGPRs (kill the L2 reload).
// R14 post-mortem: removing the memory clobber did NOT stop remat (VGPR 156,
// flat 59.7us) -- compiler remats because it MAY (const __restrict loads) and
// prefers low pressure. The missing arithmetic: per-step A-frag reload = 48KB
// x 1024 waves x 28 steps = 1.41 GB/dispatch from L2 = 23.6 TB/s = ~70% of
// the 34.5 TB/s L2 ceiling. THAT is the structure-invariant 59us wall
// (invisible in FETCH_SIZE: ws is L2-resident; insensitive to waves/barriers:
// R9-R14 all flat; VALUBusy ~50% = L2 stall).
// R15: after the one-time load, launder each a[mt][kc] through
// asm volatile("" : "+a"(...)). "a" pins into AGPRs (192 AGPR; VGPR file
// stays <256; gfx950 MFMA reads A from AGPR via AV class, no copies). An asm
// result is opaque -> remat impossible -> weights resident for all 28 steps.
// Everything else byte-identical to passing R14 (absmax 0.00195).
// Prediction: 59.7 -> 24-32us; VALUBusy 70-90%; MfmaUtil ~25%.
// Failure tells: flat -> L2 theory wrong (profile TCC_HIT); ~40us partial ->
// per-step accvgpr_read copies -> inline-asm MFMA next.

namespace {
constexpr int B_TOT   = 16384;
constexpr int T_STEPS = 28;
constexpr int IN_DIM  = 28;
constexpr int HID     = 64;
constexpr int OUT_DIM = 10;
constexpr int ROWS    = 16;    // batch rows per wave -> 1024 waves, 1/SIMD
constexpr int THREADS = 64;    // 1 wave per block
constexpr int KP      = 104;   // row stride in shorts (208 B = 13*16B)
constexpr int XROW    = T_STEPS * IN_DIM;  // 784 floats per batch row
constexpr int NFRAG   = 16 * 3;            // 16 Mtiles * 3 kchunks
constexpr int WS_ELEMS = NFRAG * 64 * 8;   // 24576 bf16 = 48 KB
}

typedef __attribute__((ext_vector_type(8))) short short8v;   // 8 bf16
typedef __attribute__((ext_vector_type(4))) short short4v;
typedef __attribute__((ext_vector_type(4))) float float4v;

// Full fence: one-time use (prologue/epilogue). Clobbers memory.
__device__ __forceinline__ void lds_fence_full() {
  asm volatile("s_waitcnt lgkmcnt(0)" ::: "memory");
  __builtin_amdgcn_sched_barrier(0);
}
// Surgical loop fence: HW drain + scheduler pin, NO value clobber.
__device__ __forceinline__ void lds_order() {
  asm volatile("s_waitcnt lgkmcnt(0)");
  __builtin_amdgcn_sched_barrier(0);
}

__device__ __forceinline__ short f2bf_cold(float f) {
  union { float f; unsigned u; } v; v.f = f;
  unsigned r = v.u + 0x7FFFu + ((v.u >> 16) & 1u);
  return (short)(r >> 16);
}
__device__ __forceinline__ float bf2f(short s) {
  union { unsigned u; float f; } v; v.u = ((unsigned)(unsigned short)s) << 16;
  return v.f;
}
__device__ __forceinline__ unsigned pk2(float a, float b) {  // 2xf32->bf16x2
  __hip_bfloat162 h = __float22bfloat162_rn(float2{a, b});
  union { __hip_bfloat162 h; unsigned u; } cv; cv.h = h; return cv.u;
}

// ---- setup: permute weights+bias into MFMA A-frag order (runs every call) --
// ws layout: frag f = mt*3 + kc, lane l, elem j:
//   ws[(f*64 + l)*8 + j] = bf16 of A[m=16*mt+(l&15)][k=kc*32+(l>>4)*8+j]
// gate row g = (m&3)*64 + (m>>2); k<28 -> W_ih, k==28 -> b_ih+b_hh,
// 29..31 -> 0, k>=32 -> W_hh[:, u(k-32)] where stored h col c holds unit
// u(c) = 4*(c&15) + (c>>4)   [pi: lane (q,l15) writes units 4mt+q at
// col 16q+mt, contiguous per lane].
// All values pre-scaled by -log2(e) (gates i,f,o) / -2*log2(e) (gate g).
__global__ void lstm_prep(const float* __restrict__ W_ih,
                          const float* __restrict__ W_hh,
                          const float* __restrict__ b_ih,
                          const float* __restrict__ b_hh,
                          unsigned short* __restrict__ ws) {
  int idx = blockIdx.x * blockDim.x + threadIdx.x;
  if (idx >= WS_ELEMS) return;
  int j  = idx & 7;
  int l  = (idx >> 3) & 63;
  int fk = idx >> 9;            // mt*3 + kc
  int kc = fk % 3;
  int mt = fk / 3;
  int m  = 16 * mt + (l & 15);
  int unit = m >> 2, type = m & 3;
  int g  = type * 64 + unit;
  int k  = kc * 32 + (l >> 4) * 8 + j;
  float v = 0.0f;
  if (k < IN_DIM)        v = W_ih[g * IN_DIM + k];
  else if (k == IN_DIM)  v = b_ih[g] + b_hh[g];
  else if (k >= 32) {
    int c = k - 32;
    int u = 4 * (c & 15) + (c >> 4);   // pi
    v = W_hh[g * HID + u];
  }
  v *= (type == 2) ? -2.8853900817779268f : -1.4426950408889634f;
  ws[idx] = (unsigned short)f2bf_cold(v);
}

__global__ __attribute__((amdgpu_flat_work_group_size(THREADS, THREADS),
                          amdgpu_waves_per_eu(1, 1)))
void lstm_wave(const float* __restrict__ x,
               const unsigned short* __restrict__ wfrag,
               const float* __restrict__ W_fc,
               const float* __restrict__ b_fc, float* __restrict__ out) {
  // wave-private: [buf][row][k]: 0..27 x, 28 = 1.0 (bias), 32..95 h (pi-perm)
  __shared__ __align__(16) short hs[2][ROWS][KP];

  const int lane = threadIdx.x & 63;
  const int l15  = lane & 15;
  const int q    = lane >> 4;     // 0..3
  const int b0   = blockIdx.x * ROWS;

  // ---- stationary A: all 16 M-tiles, 48 coalesced 16B loads per lane, then
  // pinned into AGPRs via opaque asm (cannot be rematerialized) -------------
  short8v a[16][3];
#pragma unroll
  for (int mt = 0; mt < 16; ++mt)
#pragma unroll
    for (int kc = 0; kc < 3; ++kc)
      a[mt][kc] = *(const short8v*)&wfrag[(((mt * 3) + kc) * 64 + lane) * 8];
#pragma unroll
  for (int mt = 0; mt < 16; ++mt)
#pragma unroll
    for (int kc = 0; kc < 3; ++kc)
      asm volatile("" : "+a"(a[mt][kc]));   // pin: AGPR-resident, opaque

  // zero both buffers (13 x short4 per lane), then the constant bias column
  {
    short4v z4 = {0, 0, 0, 0};
#pragma unroll
    for (int k2 = 0; k2 < 13; ++k2)
      ((short4v*)&hs[0][0][0])[lane + 64 * k2] = z4;
  }
  lds_fence_full();   // one-time: zero-stores before bias write
  if (lane < 2 * ROWS)   // buf = lane>>4, row = lane&15
    hs[lane >> 4][lane & 15][IN_DIM] = (short)0x3F80;  // bf16 1.0

  // ---- x staging: 112 float4-slots per wave; lane covers {lane, lane+64} --
  const int  s0  = lane;            // always < 112
  const int  s1  = lane + 64;
  const bool st1 = (s1 < 112);      // lanes 0..47
  const int  sr0 = s0 / 7, sc0 = s0 - 7 * sr0;
  const int  sr1 = st1 ? (s1 / 7) : 0, sc1 = st1 ? (s1 - 7 * (s1 / 7)) : 0;
  const float* xp0 = x + (size_t)(b0 + sr0) * XROW + sc0 * 4;
  const float* xp1 = x + (size_t)(b0 + sr1) * XROW + sc1 * 4;

  // stage x_0 directly; preload x_1 into in-flight registers
  float4 fly0, fly1 = {0.f, 0.f, 0.f, 0.f};
  {
    float4 x0 = *(const float4*)xp0;
    short4v sv;
    unsigned plo = pk2(x0.x, x0.y), phi = pk2(x0.z, x0.w);
    sv[0] = (short)(plo & 0xFFFF); sv[1] = (short)(plo >> 16);
    sv[2] = (short)(phi & 0xFFFF); sv[3] = (short)(phi >> 16);
    *(short4v*)&hs[0][sr0][sc0 * 4] = sv;
    if (st1) {
      float4 x1 = *(const float4*)xp1;
      unsigned qlo = pk2(x1.x, x1.y), qhi = pk2(x1.z, x1.w);
      sv[0] = (short)(qlo & 0xFFFF); sv[1] = (short)(qlo >> 16);
      sv[2] = (short)(qhi & 0xFFFF); sv[3] = (short)(qhi >> 16);
      *(short4v*)&hs[0][sr1][sc1 * 4] = sv;
    }
    fly0 = *(const float4*)(xp0 + 1 * IN_DIM);
    if (st1) fly1 = *(const float4*)(xp1 + 1 * IN_DIM);
  }
  lds_fence_full();   // one-time: staging visible before step 0 reads

  float c_state[16];
#pragma unroll
  for (int mt = 0; mt < 16; ++mt) c_state[mt] = 0.f;

  // ---- one timestep, compile-time buffer indices ---------------------------
  auto step = [&](int t, int cur, int nxt) __attribute__((always_inline)) {
    // order prior-step h/x writes before this step's reads (no value clobber)
    lds_order();

    // B-frags: lane holds B[k = kc*32 + q*8 + j][n = l15]
    short8v bf0 = *(const short8v*)&hs[cur][l15][q * 8];
    short8v bf1 = *(const short8v*)&hs[cur][l15][32 + q * 8];
    short8v bf2 = *(const short8v*)&hs[cur][l15][64 + q * 8];

    // store x_{t+1} (loaded a step ago), issue load of x_{t+2}
    if (t + 1 < T_STEPS) {
      short4v sv;
      unsigned plo = pk2(fly0.x, fly0.y), phi = pk2(fly0.z, fly0.w);
      sv[0] = (short)(plo & 0xFFFF); sv[1] = (short)(plo >> 16);
      sv[2] = (short)(phi & 0xFFFF); sv[3] = (short)(phi >> 16);
      *(short4v*)&hs[nxt][sr0][sc0 * 4] = sv;
      if (st1) {
        unsigned qlo = pk2(fly1.x, fly1.y), qhi = pk2(fly1.z, fly1.w);
        sv[0] = (short)(qlo & 0xFFFF); sv[1] = (short)(qlo >> 16);
        sv[2] = (short)(qhi & 0xFFFF); sv[3] = (short)(qhi >> 16);
        *(short4v*)&hs[nxt][sr1][sc1 * 4] = sv;
      }
      if (t + 2 < T_STEPS) {
        fly0 = *(const float4*)(xp0 + (t + 2) * IN_DIM);
        if (st1) fly1 = *(const float4*)(xp1 + (t + 2) * IN_DIM);
      }
    }

    // 16 M-tiles x 3 k-chunks; 16 independent 3-deep MFMA chains (A in AGPR)
    const float4v zero4 = {0.f, 0.f, 0.f, 0.f};
    float4v acc[16];
#pragma unroll
    for (int mt = 0; mt < 16; ++mt)
      acc[mt] = __builtin_amdgcn_mfma_f32_16x16x32_bf16(a[mt][0], bf0, zero4, 0, 0, 0);
#pragma unroll
    for (int mt = 0; mt < 16; ++mt)
      acc[mt] = __builtin_amdgcn_mfma_f32_16x16x32_bf16(a[mt][1], bf1, acc[mt], 0, 0, 0);
#pragma unroll
    for (int mt = 0; mt < 16; ++mt)
      acc[mt] = __builtin_amdgcn_mfma_f32_16x16x32_bf16(a[mt][2], bf2, acc[mt], 0, 0, 0);

    // activations: lane (q,l15) owns unit 4mt+q, row l15; regs j = i,f,g,o.
    float hv[16];
#pragma unroll
    for (int mt = 0; mt < 16; ++mt) {
      float4v g4 = acc[mt];
      float Ei = __builtin_amdgcn_exp2f(g4[0]);
      float Ef = __builtin_amdgcn_exp2f(g4[1]);
      float Eg = __builtin_amdgcn_exp2f(g4[2]);
      float Eo = __builtin_amdgcn_exp2f(g4[3]);
      float di = 1.0f + Ei, df = 1.0f + Ef;
      float r1 = __builtin_amdgcn_rcpf(di * df);
      float iv = r1 * df;
      float fv = r1 * di;
      float gv = fmaf(2.0f, __builtin_amdgcn_rcpf(1.0f + Eg), -1.0f);
      float cn = fmaf(fv, c_state[mt], iv * gv);
      c_state[mt] = cn;
      float ct = fminf(fmaxf(cn, -15.0f), 15.0f);   // tanh saturated beyond
      float Ec = __builtin_amdgcn_exp2f(-2.8853900817779268f * ct);
      float dn = 1.0f + Eo, dc = 1.0f + Ec;
      float r2 = __builtin_amdgcn_rcpf(dn * dc);
      float ov = r2 * dc;
      float tc = fmaf(2.0f * r2, dn, -1.0f);
      hv[mt] = ov * tc;
    }

    // pack 16 bf16 (units 4mt+q at cols 16q+mt, mt ascending) -> 2x b128
    union { unsigned u[4]; short8v s; } uh0, uh1;
#pragma unroll
    for (int p = 0; p < 4; ++p) uh0.u[p] = pk2(hv[2 * p], hv[2 * p + 1]);
#pragma unroll
    for (int p = 0; p < 4; ++p) uh1.u[p] = pk2(hv[8 + 2 * p], hv[9 + 2 * p]);
    *(short8v*)&hs[nxt][l15][32 + 16 * q]     = uh0.s;
    *(short8v*)&hs[nxt][l15][32 + 16 * q + 8] = uh1.s;
  };

  // unrolled x2: compile-time cur/nxt -> static aliasing enforces ordering
  for (int tt = 0; tt < T_STEPS / 2; ++tt) {
    step(2 * tt,     0, 1);
    step(2 * tt + 1, 1, 0);
  }

  lds_fence_full();   // one-time: final h-writes before cross-lane epilogue

  // ---- FC epilogue: final h in hs[0]; stored col c holds unit u(c) --------
  {
    const int er = lane >> 2;      // 0..15
    const int eo = lane & 3;       // 0..3
    float s0a = b_fc[eo];
    float s1a = b_fc[eo + 4];
    float s2a = (eo < 2) ? b_fc[eo + 8] : 0.f;
#pragma unroll
    for (int c = 0; c < HID; ++c) {
      float hb = bf2f(hs[0][er][32 + c]);
      int u = 4 * (c & 15) + (c >> 4);
      s0a = fmaf(hb, W_fc[eo * HID + u], s0a);
      s1a = fmaf(hb, W_fc[(eo + 4) * HID + u], s1a);
      if (eo < 2) s2a = fmaf(hb, W_fc[(eo + 8) * HID + u], s2a);
    }
    float* orow = out + (size_t)(b0 + er) * OUT_DIM;
    orow[eo]     = s0a;
    orow[eo + 4] = s1a;
    if (eo < 2) orow[eo + 8] = s2a;
  }
}

extern "C" void kernel_launch(void* const* d_in, const int* in_sizes, int n_in,
                              void* d_out, int out_size, void* d_ws, size_t ws_size,
                              hipStream_t stream) {
  const float* x    = (const float*)d_in[0];
  const float* W_ih = (const float*)d_in[1];
  const float* W_hh = (const float*)d_in[2];
  const float* b_ih = (const float*)d_in[3];
  const float* b_hh = (const float*)d_in[4];
  const float* W_fc = (const float*)d_in[5];
  const float* b_fc = (const float*)d_in[6];
  float* out = (float*)d_out;
  unsigned short* ws = (unsigned short*)d_ws;   // 48 KB frag-ordered weights

  lstm_prep<<<(WS_ELEMS + 255) / 256, 256, 0, stream>>>(W_ih, W_hh, b_ih, b_hh, ws);

  dim3 grid(B_TOT / ROWS);   // 1024 one-wave blocks -> 1 wave/SIMD chip-wide
  dim3 block(THREADS);
  lstm_wave<<<grid, block, 0, stream>>>(x, ws, W_fc, b_fc, out);
}